// Round 1
// baseline (149.005 us; speedup 1.0000x reference)
//
#include <hip/hip_runtime.h>

// Problem constants (from reference): B=4, K=8, H=W=64 -> N=4096, D=64.
#define BATCH  4
#define KBITS  8
#define NPOS   4096
#define DDIM   64
#define NCODES 256

// ---------------------------------------------------------------------------
// K1: one block per batch. Compute 8-bit codes from z (>0.5 per bit) and a
// shared-memory histogram of codes over evidence positions.
// ---------------------------------------------------------------------------
__global__ void k_codes_hist(const float* __restrict__ z,
                             const int* __restrict__ evidence_mask,
                             unsigned char* __restrict__ codes,
                             int* __restrict__ hist) {
    const int b = blockIdx.x;
    const int tid = threadIdx.x;  // 256 threads
    __shared__ int h[NCODES];
    h[tid] = 0;
    __syncthreads();

    const float* zb = z + (size_t)b * KBITS * NPOS;
    for (int n = tid; n < NPOS; n += 256) {
        int code = 0;
#pragma unroll
        for (int k = 0; k < KBITS; ++k) {
            code |= (int)(zb[k * NPOS + n] > 0.5f) << k;
        }
        codes[b * NPOS + n] = (unsigned char)code;
        if (evidence_mask[b * NPOS + n] != 0) {
            atomicAdd(&h[code], 1);
        }
    }
    __syncthreads();
    hist[b * NCODES + tid] = h[tid];
}

// ---------------------------------------------------------------------------
// K2: one block per (batch, query-code), 64 threads = one per d.
// out_row[b][cq][d] = sum_c cnt[c]*exp((minpop - pop(cq^c))/t)*VT[c][d] / denom
// Matches reference softmax shift (m = -minpop/t); all-masked batch -> 0.
// ---------------------------------------------------------------------------
__global__ void k_table(const int* __restrict__ hist,
                        const float* __restrict__ value_table,
                        const float* __restrict__ temperature,
                        float* __restrict__ rowg) {
    const int b  = blockIdx.x >> 8;
    const int cq = blockIdx.x & 255;
    const int d  = threadIdx.x;  // 0..63, one full wave

    __shared__ int cnt[NCODES];
#pragma unroll
    for (int i = 0; i < 4; ++i) cnt[d + 64 * i] = hist[b * NCODES + d + 64 * i];
    __syncthreads();

    // min popcount distance over codes present in evidence (softmax max-shift)
    int mn = 1 << 20;
#pragma unroll
    for (int i = 0; i < 4; ++i) {
        int c = d + 64 * i;
        if (cnt[c] > 0) mn = min(mn, __popc(cq ^ c));
    }
#pragma unroll
    for (int off = 32; off > 0; off >>= 1) mn = min(mn, __shfl_down(mn, off));
    mn = __shfl(mn, 0);

    const float t = fmaxf(temperature[0], 0.1f);
    const float inv_t = 1.0f / t;
    float wtab[KBITS + 1];
#pragma unroll
    for (int j = 0; j <= KBITS; ++j) {
        // if no evidence at all, mn is huge -> wtab=inf, but guarded by cnt>0
        wtab[j] = expf((float)(mn - j) * inv_t);
    }

    float denom = 0.0f, acc = 0.0f;
    for (int c = 0; c < NCODES; ++c) {
        int ct = cnt[c];
        if (ct > 0) {
            float w = (float)ct * wtab[__popc(cq ^ c)];
            denom += w;
            acc   += w * value_table[c * DDIM + d];
        }
    }
    rowg[(((b << 8) + cq) << 6) + d] = acc / fmaxf(denom, 1e-20f);
}

// ---------------------------------------------------------------------------
// K3: gather. out layout (B, D, N): out[(b*D + d)*N + n] = row[b][codes[b][n]][d]
// Consecutive threads -> consecutive n: coalesced code read + output write.
// ---------------------------------------------------------------------------
__global__ void k_gather(const unsigned char* __restrict__ codes,
                         const float* __restrict__ rowg,
                         float* __restrict__ out) {
    const int gid = blockIdx.x * 256 + threadIdx.x;  // < B*D*N = 1048576
    const int n  = gid & (NPOS - 1);
    const int bd = gid >> 12;       // NPOS = 2^12
    const int d  = bd & (DDIM - 1);
    const int b  = bd >> 6;         // DDIM = 2^6
    const int code = codes[b * NPOS + n];
    out[gid] = rowg[(((b << 8) + code) << 6) + d];
}

extern "C" void kernel_launch(void* const* d_in, const int* in_sizes, int n_in,
                              void* d_out, int out_size, void* d_ws, size_t ws_size,
                              hipStream_t stream) {
    const float* z            = (const float*)d_in[0];  // (B,K,H,W) fp32
    const int*   evidence     = (const int*)d_in[1];    // (B,N) bool -> int32
    const float* temperature  = (const float*)d_in[2];  // scalar
    const float* value_table  = (const float*)d_in[3];  // (256,D) fp32
    // d_in[4] = mask_value: provably never contributes (attn==0 off-evidence)
    // d_in[5] = pop_lut: replaced by __popc (identical values)

    float* out = (float*)d_out;  // (B,D,H,W) fp32, 1048576 elements

    // Workspace layout
    unsigned char* codes = (unsigned char*)d_ws;                 // 16384 B
    int*           hist  = (int*)((char*)d_ws + 16384);          //  4096 B
    float*         rowg  = (float*)((char*)d_ws + 20480);        // 262144 B

    k_codes_hist<<<BATCH, 256, 0, stream>>>(z, evidence, codes, hist);
    k_table<<<BATCH * NCODES, 64, 0, stream>>>(hist, value_table, temperature, rowg);
    k_gather<<<(BATCH * DDIM * NPOS) / 256, 256, 0, stream>>>(codes, rowg, out);
}

// Round 2
// 78.898 us; speedup vs baseline: 1.8886x; 1.8886x over previous
//
#include <hip/hip_runtime.h>

// Problem constants: B=4, K=8, H=W=64 -> N=4096, D=64, codes are 8-bit.
#define BATCH  4
#define KBITS  8
#define NPOS   4096
#define DDIM   64
#define NCODES 256

// ---------------------------------------------------------------------------
// K1: 16 blocks per batch (grid=64), 256 threads. Each thread handles one
// position: compute 8-bit code from z>0.5, write codes, LDS histogram of
// evidence codes, then one global atomicAdd per non-empty bin.
// hist must be zeroed beforehand (hipMemsetAsync in kernel_launch).
// ---------------------------------------------------------------------------
__global__ void k_codes_hist(const float* __restrict__ z,
                             const int* __restrict__ evidence_mask,
                             unsigned char* __restrict__ codes,
                             int* __restrict__ hist) {
    const int b  = blockIdx.x >> 4;
    const int n0 = (blockIdx.x & 15) * 256;
    const int tid = threadIdx.x;
    const int n = n0 + tid;

    __shared__ int h[NCODES];
    h[tid] = 0;
    __syncthreads();

    const float* zb = z + (size_t)b * KBITS * NPOS;
    int code = 0;
#pragma unroll
    for (int k = 0; k < KBITS; ++k) {
        code |= (int)(zb[k * NPOS + n] > 0.5f) << k;
    }
    codes[b * NPOS + n] = (unsigned char)code;
    if (evidence_mask[b * NPOS + n] != 0) {
        atomicAdd(&h[code], 1);
    }
    __syncthreads();
    if (h[tid] != 0) atomicAdd(&hist[b * NCODES + tid], h[tid]);
}

// ---------------------------------------------------------------------------
// K2: one block per (batch, query-code), 256 threads = 4 waves.
// rowg[b][cq][d] = sum_c cnt[c]*exp((mn - pop(cq^c))/t)*VT[c][d] / denom
// Branchless: per-code weight wrow[c] precomputed in LDS; c-loop split
// across 4 waves (64 codes each) then LDS cross-wave reduction.
// All-masked batch (mn stays 99) -> weights 0 -> output 0 (matches ref).
// ---------------------------------------------------------------------------
__global__ void k_table(const int* __restrict__ hist,
                        const float* __restrict__ value_table,
                        const float* __restrict__ temperature,
                        float* __restrict__ rowg) {
    const int b  = blockIdx.x >> 8;
    const int cq = blockIdx.x & 255;
    const int tid = threadIdx.x;      // 0..255
    const int wv  = tid >> 6;         // wave 0..3
    const int d   = tid & 63;         // lane / output dim

    __shared__ float wrow[NCODES];
    __shared__ float accs[4][DDIM];
    __shared__ float dens[4];
    __shared__ int   mns[4];

    // --- per-code weight precompute -------------------------------------
    const int cnt = hist[b * NCODES + tid];
    const int pop = __popc(cq ^ tid);
    int myMn = (cnt > 0) ? pop : 99;
#pragma unroll
    for (int off = 32; off > 0; off >>= 1) myMn = min(myMn, __shfl_down(myMn, off));
    if (d == 0) mns[wv] = myMn;
    __syncthreads();
    const int mn = min(min(mns[0], mns[1]), min(mns[2], mns[3]));

    const float inv_t = 1.0f / fmaxf(temperature[0], 0.1f);
    wrow[tid] = (mn > KBITS) ? 0.0f
                             : (float)cnt * __expf((float)(mn - pop) * inv_t);
    __syncthreads();

    // --- 64 codes per wave: branchless FMA chain, coalesced VT loads ----
    float acc = 0.0f, den = 0.0f;
#pragma unroll
    for (int i = 0; i < 64; ++i) {
        const int cc = wv * 64 + i;
        const float w = wrow[cc];                    // uniform addr: broadcast
        den += w;
        acc = fmaf(w, value_table[cc * DDIM + d], acc);
    }

    // --- cross-wave reduction -------------------------------------------
    accs[wv][d] = acc;
    if (d == 0) dens[wv] = den;
    __syncthreads();
    if (wv == 0) {
        float a  = accs[0][d] + accs[1][d] + accs[2][d] + accs[3][d];
        float dn = dens[0] + dens[1] + dens[2] + dens[3];
        rowg[(((b << 8) + cq) << 6) + d] = a / fmaxf(dn, 1e-20f);
    }
}

// ---------------------------------------------------------------------------
// K3: gather. out (B, D, N): out[(b*D+d)*N + n] = rowg[b][codes[b][n]][d]
// 4 elements per thread: uchar4 code load, float4 store.
// ---------------------------------------------------------------------------
__global__ void k_gather(const unsigned char* __restrict__ codes,
                         const float* __restrict__ rowg,
                         float* __restrict__ out) {
    const int gid  = blockIdx.x * 256 + threadIdx.x;   // < 262144
    const int base = gid * 4;                          // element index
    const int n4   = base & (NPOS - 1);                // multiple of 4
    const int bd   = base >> 12;                       // NPOS = 2^12
    const int d    = bd & (DDIM - 1);
    const int b    = bd >> 6;

    const uchar4 c4 = *(const uchar4*)(codes + b * NPOS + n4);
    const float* rb = rowg + ((b << 8) << 6) + d;
    float4 o;
    o.x = rb[(int)c4.x << 6];
    o.y = rb[(int)c4.y << 6];
    o.z = rb[(int)c4.z << 6];
    o.w = rb[(int)c4.w << 6];
    *(float4*)(out + base) = o;
}

extern "C" void kernel_launch(void* const* d_in, const int* in_sizes, int n_in,
                              void* d_out, int out_size, void* d_ws, size_t ws_size,
                              hipStream_t stream) {
    const float* z            = (const float*)d_in[0];  // (B,K,H,W) fp32
    const int*   evidence     = (const int*)d_in[1];    // (B,N) bool->int32
    const float* temperature  = (const float*)d_in[2];  // scalar
    const float* value_table  = (const float*)d_in[3];  // (256,D) fp32
    // d_in[4] mask_value: never contributes (attn==0 off-evidence)
    // d_in[5] pop_lut: replaced by __popc

    float* out = (float*)d_out;  // (B,D,H,W) fp32

    unsigned char* codes = (unsigned char*)d_ws;            // 16384 B
    int*           hist  = (int*)((char*)d_ws + 16384);     //  4096 B
    float*         rowg  = (float*)((char*)d_ws + 20480);   // 262144 B

    hipMemsetAsync(hist, 0, BATCH * NCODES * sizeof(int), stream);
    k_codes_hist<<<BATCH * 16, 256, 0, stream>>>(z, evidence, codes, hist);
    k_table<<<BATCH * NCODES, 256, 0, stream>>>(hist, value_table, temperature, rowg);
    k_gather<<<(BATCH * DDIM * NPOS) / (256 * 4), 256, 0, stream>>>(codes, rowg, out);
}